// Round 2
// baseline (165.991 us; speedup 1.0000x reference)
//
#include <hip/hip_runtime.h>

typedef unsigned short ushort_t;
typedef unsigned int uint_t;

typedef __bf16 bf16x8 __attribute__((ext_vector_type(8)));
typedef float f32x4 __attribute__((ext_vector_type(4)));

#define KK 588       // true K
#define KP 608       // padded K (19 * 32) -- B only
#define NN 1152      // N (output cols)
#define MM 32768     // M (output rows)
#define POSROWS 4096 // h*w per image
#define NSTEP 19     // KP/32
#define GRID 2304    // (MM/128) * (NN/128) = 256 * 9

// ---------------- helpers ----------------

__device__ __forceinline__ void cubic_taps(int dst, float* w, int* idx) {
    const float A = -0.75f;
    float src = (float)dst * 0.25f - 0.25f;   // (dst+0.5)*16/64 - 0.5
    int x0 = (int)floorf(src);
    #pragma unroll
    for (int k = -1; k <= 2; ++k) {
        int i = x0 + k;
        int ic = i < 0 ? 0 : (i > 15 ? 15 : i);
        float d = fabsf(src - (float)i);
        float wt;
        if (d <= 1.0f)      wt = ((A + 2.0f) * d - (A + 3.0f)) * d * d + 1.0f;
        else if (d < 2.0f)  wt = ((A * d - 5.0f * A) * d + 8.0f * A) * d - 4.0f * A;
        else                wt = 0.0f;
        w[k + 1] = wt;
        idx[k + 1] = ic;
    }
}

// ---------------- pos embedding: (4096, 1152) fp32 into ws ----------------

__global__ void pos_kernel(const float* __restrict__ pt, float* __restrict__ pos) {
    int n = blockIdx.x; // 0..4095 (rearranged row)
    int h = ((n >> 7) << 1) | ((n >> 1) & 1);
    int w = (((n >> 2) & 31) << 1) | (n & 1);
    float wh[4], ww[4];
    int ih[4], iw[4];
    cubic_taps(h, wh, ih);
    cubic_taps(w, ww, iw);
    for (int j = threadIdx.x; j < NN; j += blockDim.x) {
        float s = 0.f;
        #pragma unroll
        for (int a = 0; a < 4; ++a) {
            float rs = 0.f;
            #pragma unroll
            for (int b = 0; b < 4; ++b)
                rs += ww[b] * pt[(ih[a] * 16 + iw[b]) * NN + j];
            s += wh[a] * rs;
        }
        pos[(size_t)n * NN + j] = s;
    }
}

// ---------------- f32 -> bf16 with K padding 588 -> 608 (B only) ----------------

__global__ void cvt_pad_kernel(const float* __restrict__ src, ushort_t* __restrict__ dst,
                               int rows) {
    int idx = blockIdx.x * 256 + threadIdx.x;
    int total = rows * KP;
    if (idx >= total) return;
    int row = idx / KP;
    int k = idx - row * KP;
    float v = (k < KK) ? src[(size_t)row * KK + k] : 0.0f;
    union { float f; uint_t u; } c; c.f = v;
    uint_t u = c.u;
    dst[idx] = (ushort_t)((u + 0x7FFFu + ((u >> 16) & 1u)) >> 16);
}

// ---------------- fused bf16 MFMA GEMM: A fp32 -> bf16 in-kernel ----------------
// A: [MM][KK] fp32 (pixel values), B: [NN][KP] bf16 (w_patch rows = out cols)
// out[m][n] = sum_k A[m][k]*B[n][k] + bias[n] + pos[m & 4095][n]
// 2-phase pipeline: issue next-tile loads BEFORE compute, single barrier per K-step.

__global__ void gemm_kernel(const float* __restrict__ A,
                            const ushort_t* __restrict__ Bbf,
                            const float* __restrict__ bias,
                            const float* __restrict__ pos,
                            float* __restrict__ out) {
    __shared__ __align__(16) ushort_t lA[2][128 * 32]; // [row][32k] bf16, 16B-slot swizzled
    __shared__ __align__(16) ushort_t lB[2][128 * 32];

    const int t = threadIdx.x;
    const int lane = t & 63;
    const int wid = t >> 6;
    const int wm = wid >> 1, wn = wid & 1;

    // bijective XCD-chunked swizzle: 2304 = 8 XCDs x 288; 9 consecutive
    // locals share one A panel (L2-resident) per XCD.
    int linear = (int)blockIdx.x;
    int xcd = linear & 7;
    int local = linear >> 3;
    int wg = xcd * (GRID / 8) + local;
    int mt = wg / 9;
    int nt = wg - mt * 9;
    const int bm = mt * 128;
    const int bn = nt * 128;

    f32x4 acc[4][4] = {};
    f32x4 areg[2][2]; // staged A fp32: [chunk j][half], 32B of one row per chunk

    auto loadA = [&](int ks) {
        const int k0 = ks * 32;
        if (k0 + 32 <= KK) { // uniform fast path (ks <= 17)
            #pragma unroll
            for (int j = 0; j < 2; ++j) {
                int idx = j * 256 + t;
                int row = idx >> 2, q = idx & 3;
                const float* g = A + (size_t)(bm + row) * KK + k0 + q * 8;
                areg[j][0] = *(const f32x4*)g;
                areg[j][1] = *(const f32x4*)(g + 4);
            }
        } else { // last K-step: guard + zero-pad 588..607
            #pragma unroll
            for (int j = 0; j < 2; ++j) {
                int idx = j * 256 + t;
                int row = idx >> 2, q = idx & 3;
                int kbase = k0 + q * 8;
                const float* g = A + (size_t)(bm + row) * KK + kbase;
                #pragma unroll
                for (int e = 0; e < 4; ++e) {
                    areg[j][0][e] = (kbase + e < KK) ? g[e] : 0.f;
                    areg[j][1][e] = (kbase + 4 + e < KK) ? g[4 + e] : 0.f;
                }
            }
        }
    };

    auto writeA = [&](int buf) {
        #pragma unroll
        for (int j = 0; j < 2; ++j) {
            int idx = j * 256 + t;
            int row = idx >> 2, q = idx & 3;
            int qs = q ^ ((row >> 1) & 3); // direct LDS swizzle (ds_write can scatter)
            bf16x8 v;
            #pragma unroll
            for (int e = 0; e < 4; ++e) {
                v[e]     = (__bf16)areg[j][0][e];
                v[e + 4] = (__bf16)areg[j][1][e];
            }
            *(bf16x8*)(&lA[buf][row * 32 + qs * 8]) = v;
        }
    };

    auto stageB = [&](int ks, int buf) {
        const int k0 = ks * 32;
        #pragma unroll
        for (int j = 0; j < 2; ++j) {
            int idx = j * 256 + t;
            int row = idx >> 2, slot = idx & 3;
            int khi = slot ^ ((row >> 1) & 3); // inverse swizzle on SOURCE (lds dest linear)
            const ushort_t* gB = Bbf + (size_t)(bn + row) * KP + k0 + khi * 8;
            ushort_t* lBp = &lB[buf][(size_t)(idx & ~63) * 8]; // wave-uniform base
            __builtin_amdgcn_global_load_lds(
                (const __attribute__((address_space(1))) void*)gB,
                (__attribute__((address_space(3))) void*)lBp, 16, 0, 0);
        }
    };

    // prologue
    loadA(0);
    stageB(0, 0);
    writeA(0);
    __syncthreads();

    for (int ks = 0; ks < NSTEP; ++ks) {
        const int cur = ks & 1, nxt = cur ^ 1;
        const bool more = (ks + 1 < NSTEP);
        if (more) {           // issue next-tile loads FIRST (in flight during MFMA)
            loadA(ks + 1);
            stageB(ks + 1, nxt);
        }

        bf16x8 af[4], bfr[4];
        #pragma unroll
        for (int mi = 0; mi < 4; ++mi) {
            int row = wm * 64 + mi * 16 + (lane & 15);
            int slot = (lane >> 4) ^ ((row >> 1) & 3);
            af[mi] = *(const bf16x8*)(&lA[cur][row * 32 + slot * 8]);
        }
        #pragma unroll
        for (int ni = 0; ni < 4; ++ni) {
            int row = wn * 64 + ni * 16 + (lane & 15);
            int slot = (lane >> 4) ^ ((row >> 1) & 3);
            bfr[ni] = *(const bf16x8*)(&lB[cur][row * 32 + slot * 8]);
        }
        #pragma unroll
        for (int mi = 0; mi < 4; ++mi)
            #pragma unroll
            for (int ni = 0; ni < 4; ++ni)
                acc[mi][ni] = __builtin_amdgcn_mfma_f32_16x16x32_bf16(
                    af[mi], bfr[ni], acc[mi][ni], 0, 0, 0);

        if (more) writeA(nxt); // cvt + ds_write next A tile (waits its own loads only)
        __syncthreads();       // single vmcnt(0)+barrier per K-step, AFTER compute
    }

    // epilogue: C/D layout col = lane&15, row = (lane>>4)*4 + r
    #pragma unroll
    for (int mi = 0; mi < 4; ++mi) {
        #pragma unroll
        for (int ni = 0; ni < 4; ++ni) {
            int col = bn + wn * 64 + ni * 16 + (lane & 15);
            float bcol = bias[col];
            #pragma unroll
            for (int r = 0; r < 4; ++r) {
                int row = bm + wm * 64 + mi * 16 + (lane >> 4) * 4 + r;
                int prow = row & (POSROWS - 1);
                out[(size_t)row * NN + col] =
                    acc[mi][ni][r] + bcol + pos[(size_t)prow * NN + col];
            }
        }
    }
}

// ---------------- fallback (ws too small): naive fp32 ----------------

__global__ void fb_kernel(const float* __restrict__ A, const float* __restrict__ W,
                          const float* __restrict__ bias, const float* __restrict__ pt,
                          float* __restrict__ out) {
    __shared__ float sA[16][17], sB[16][17];
    int ty = threadIdx.y, tx = threadIdx.x;
    int row = blockIdx.y * 16 + ty; // M
    int col = blockIdx.x * 16 + tx; // N
    float acc = 0.f;
    for (int k0 = 0; k0 < KK; k0 += 16) {
        int ka = k0 + tx;
        sA[ty][tx] = (ka < KK) ? A[(size_t)row * KK + ka] : 0.f;
        sB[ty][tx] = (ka < KK) ? W[(size_t)(blockIdx.x * 16 + ty) * KK + ka] : 0.f;
        __syncthreads();
        #pragma unroll
        for (int kk = 0; kk < 16; ++kk)
            acc += sA[ty][kk] * sB[tx][kk];
        __syncthreads();
    }
    int n = row & (POSROWS - 1);
    int h = ((n >> 7) << 1) | ((n >> 1) & 1);
    int w = (((n >> 2) & 31) << 1) | (n & 1);
    float wh[4], ww[4]; int ih[4], iw[4];
    cubic_taps(h, wh, ih);
    cubic_taps(w, ww, iw);
    float p = 0.f;
    #pragma unroll
    for (int a = 0; a < 4; ++a) {
        float rs = 0.f;
        #pragma unroll
        for (int b = 0; b < 4; ++b)
            rs += ww[b] * pt[(ih[a] * 16 + iw[b]) * NN + col];
        p += wh[a] * rs;
    }
    out[(size_t)row * NN + col] = acc + bias[col] + p;
}

// ---------------- launch ----------------

extern "C" void kernel_launch(void* const* d_in, const int* in_sizes, int n_in,
                              void* d_out, int out_size, void* d_ws, size_t ws_size,
                              hipStream_t stream) {
    const float* pv   = (const float*)d_in[0]; // (32768, 588)
    const float* wp   = (const float*)d_in[1]; // (1152, 588)
    const float* bias = (const float*)d_in[2]; // (1152,)
    const float* pt   = (const float*)d_in[3]; // (256, 1152)
    float* out = (float*)d_out;

    const size_t pos_bytes = (size_t)POSROWS * NN * 4;   // 18,874,368
    const size_t wb_bytes  = (size_t)NN * KP * 2;        //  1,400,832
    const size_t need = pos_bytes + wb_bytes;

    if (ws_size >= need) {
        float* pos = (float*)d_ws;
        ushort_t* wb = (ushort_t*)((char*)d_ws + pos_bytes);

        pos_kernel<<<POSROWS, 256, 0, stream>>>(pt, pos);

        int tot_w = NN * KP;
        cvt_pad_kernel<<<(tot_w + 255) / 256, 256, 0, stream>>>(wp, wb, NN);

        gemm_kernel<<<GRID, 256, 0, stream>>>(pv, wb, bias, pos, out);
    } else {
        fb_kernel<<<dim3(NN / 16, MM / 16), dim3(16, 16), 0, stream>>>(pv, wp, bias, pt, out);
    }
}

// Round 3
// 131.911 us; speedup vs baseline: 1.2584x; 1.2584x over previous
//
#include <hip/hip_runtime.h>

typedef unsigned short ushort_t;
typedef unsigned int uint_t;

typedef __bf16 bf16x8 __attribute__((ext_vector_type(8)));
typedef float f32x4 __attribute__((ext_vector_type(4)));

#define KK 588       // true K
#define KP 608       // padded K (19 * 32)
#define NN 1152      // N (output cols)
#define MM 32768     // M (output rows)
#define POSROWS 4096 // h*w per image
#define NSTEP 19     // KP/32
#define GRID 2304    // (MM/128) * (NN/128) = 256 * 9
#define CHUNKS_PER_ROW 76 // KP/8

// ---------------- helpers ----------------

__device__ __forceinline__ void cubic_taps(int dst, float* w, int* idx) {
    const float A = -0.75f;
    float src = (float)dst * 0.25f - 0.25f;   // (dst+0.5)*16/64 - 0.5
    int x0 = (int)floorf(src);
    #pragma unroll
    for (int k = -1; k <= 2; ++k) {
        int i = x0 + k;
        int ic = i < 0 ? 0 : (i > 15 ? 15 : i);
        float d = fabsf(src - (float)i);
        float wt;
        if (d <= 1.0f)      wt = ((A + 2.0f) * d - (A + 3.0f)) * d * d + 1.0f;
        else if (d < 2.0f)  wt = ((A * d - 5.0f * A) * d + 8.0f * A) * d - 4.0f * A;
        else                wt = 0.0f;
        w[k + 1] = wt;
        idx[k + 1] = ic;
    }
}

// ---------------- pos embedding: (4096, 1152) fp32 into ws ----------------
// one block per rearranged row; threads cover 1152 floats as 288 f32x4 chunks

__global__ void pos_kernel(const float* __restrict__ pt, float* __restrict__ pos) {
    int n = blockIdx.x; // 0..4095 (rearranged row)
    int h = ((n >> 7) << 1) | ((n >> 1) & 1);
    int w = (((n >> 2) & 31) << 1) | (n & 1);
    float wh[4], ww[4];
    int ih[4], iw[4];
    cubic_taps(h, wh, ih);
    cubic_taps(w, ww, iw);
    int tid = threadIdx.x;
    if (tid >= NN / 4) return;
    const f32x4* pt4 = (const f32x4*)pt;
    f32x4 s = {0.f, 0.f, 0.f, 0.f};
    #pragma unroll
    for (int a = 0; a < 4; ++a) {
        #pragma unroll
        for (int b = 0; b < 4; ++b) {
            float wt = wh[a] * ww[b];
            f32x4 v = pt4[(ih[a] * 16 + iw[b]) * (NN / 4) + tid];
            s.x += wt * v.x; s.y += wt * v.y; s.z += wt * v.z; s.w += wt * v.w;
        }
    }
    ((f32x4*)pos)[(size_t)n * (NN / 4) + tid] = s;
}

// ---------------- f32 -> bf16, 8 elems/thread, K padded 588 -> 608 ----------------

__global__ void cvt_pad_kernel(const float* __restrict__ src, ushort_t* __restrict__ dst,
                               int rows) {
    int c = blockIdx.x * 256 + threadIdx.x; // chunk id, 8 elems each
    if (c >= rows * CHUNKS_PER_ROW) return;
    int row = c / CHUNKS_PER_ROW;
    int k0 = (c - row * CHUNKS_PER_ROW) * 8;
    const float* g = src + (size_t)row * KK + k0;
    bf16x8 v;
    if (k0 + 8 <= KK) { // full chunk (k0 <= 580)
        f32x4 a = *(const f32x4*)g;
        f32x4 b = *(const f32x4*)(g + 4);
        #pragma unroll
        for (int e = 0; e < 4; ++e) { v[e] = (__bf16)a[e]; v[e + 4] = (__bf16)b[e]; }
    } else {
        #pragma unroll
        for (int e = 0; e < 8; ++e)
            v[e] = (k0 + e < KK) ? (__bf16)g[e] : (__bf16)0.f;
    }
    *(bf16x8*)(dst + (size_t)row * KP + k0) = v;
}

// ---------------- bf16 MFMA GEMM + bias + pos epilogue ----------------
// A: [MM][KP] bf16, B: [NN][KP] bf16 (w_patch rows = out cols)
// out[m][n] = sum_k A[m][k]*B[n][k] + bias[n] + pos[m & 4095][n]
// 3-deep global_load_lds pipeline with counted vmcnt + raw s_barrier (T3+T4).

__global__ void gemm_kernel(const ushort_t* __restrict__ Abf,
                            const ushort_t* __restrict__ Bbf,
                            const float* __restrict__ bias,
                            const float* __restrict__ pos,
                            float* __restrict__ out) {
    __shared__ __align__(16) ushort_t lA[3][128 * 32]; // [row][32k], 16B slots swizzled
    __shared__ __align__(16) ushort_t lB[3][128 * 32];

    const int t = threadIdx.x;
    const int lane = t & 63;
    const int wid = t >> 6;
    const int wm = wid >> 1, wn = wid & 1;

    // bijective XCD-chunked swizzle: 2304 = 8 XCDs x 288; 9 consecutive
    // locals share one A panel + pos panel per XCD.
    int linear = (int)blockIdx.x;
    int xcd = linear & 7;
    int local = linear >> 3;
    int wg = xcd * (GRID / 8) + local;
    int mt = wg / 9;
    int nt = wg - mt * 9;
    const int bm = mt * 128;
    const int bn = nt * 128;

    f32x4 acc[4][4] = {};

    auto stage = [&](int ks, int buf) {
        const int k0 = ks * 32;
        #pragma unroll
        for (int j = 0; j < 2; ++j) {
            int idx = j * 256 + t;
            int row = idx >> 2;
            int slot = idx & 3;
            int khi = slot ^ ((row >> 1) & 3); // inverse swizzle on SOURCE (lds dest linear)
            const ushort_t* gA = Abf + (size_t)(bm + row) * KP + k0 + khi * 8;
            const ushort_t* gB = Bbf + (size_t)(bn + row) * KP + k0 + khi * 8;
            ushort_t* lAp = &lA[buf][(size_t)(idx & ~63) * 8]; // wave-uniform base, 16B/lane
            ushort_t* lBp = &lB[buf][(size_t)(idx & ~63) * 8];
            __builtin_amdgcn_global_load_lds(
                (const __attribute__((address_space(1))) void*)gA,
                (__attribute__((address_space(3))) void*)lAp, 16, 0, 0);
            __builtin_amdgcn_global_load_lds(
                (const __attribute__((address_space(1))) void*)gB,
                (__attribute__((address_space(3))) void*)lBp, 16, 0, 0);
        }
    };

    // prologue: 2 tiles in flight
    stage(0, 0);
    stage(1, 1);

    for (int ks = 0; ks < NSTEP; ++ks) {
        const int cur = ks % 3;

        if (ks + 2 < NSTEP) {
            stage(ks + 2, (ks + 2) % 3);              // 4 more loads in flight
            asm volatile("s_waitcnt vmcnt(8)" ::: "memory"); // tile ks landed; ks+1/ks+2 fly
        } else if (ks + 1 < NSTEP) {
            asm volatile("s_waitcnt vmcnt(4)" ::: "memory"); // tile ks landed; ks+1 flies
        } else {
            asm volatile("s_waitcnt vmcnt(0)" ::: "memory"); // last tile landed
        }
        __builtin_amdgcn_s_barrier();   // all waves' tile-ks loads complete
        __builtin_amdgcn_sched_barrier(0);

        bf16x8 af[4], bfr[4];
        #pragma unroll
        for (int mi = 0; mi < 4; ++mi) {
            int row = wm * 64 + mi * 16 + (lane & 15);
            int slot = (lane >> 4) ^ ((row >> 1) & 3);
            af[mi] = *(const bf16x8*)(&lA[cur][row * 32 + slot * 8]);
        }
        #pragma unroll
        for (int ni = 0; ni < 4; ++ni) {
            int row = wn * 64 + ni * 16 + (lane & 15);
            int slot = (lane >> 4) ^ ((row >> 1) & 3);
            bfr[ni] = *(const bf16x8*)(&lB[cur][row * 32 + slot * 8]);
        }
        #pragma unroll
        for (int mi = 0; mi < 4; ++mi)
            #pragma unroll
            for (int ni = 0; ni < 4; ++ni)
                acc[mi][ni] = __builtin_amdgcn_mfma_f32_16x16x32_bf16(
                    af[mi], bfr[ni], acc[mi][ni], 0, 0, 0);

        // ds_reads of buf[cur] are done (they precede the MFMAs' lgkm waits);
        // fence + barrier so no wave restages buf[cur] (at iter ks+1) early.
        asm volatile("s_waitcnt lgkmcnt(0)" ::: "memory");
        __builtin_amdgcn_s_barrier();
    }

    // epilogue: C/D layout col = lane&15, row = (lane>>4)*4 + r
    #pragma unroll
    for (int mi = 0; mi < 4; ++mi) {
        #pragma unroll
        for (int ni = 0; ni < 4; ++ni) {
            int col = bn + wn * 64 + ni * 16 + (lane & 15);
            float bcol = bias[col];
            #pragma unroll
            for (int r = 0; r < 4; ++r) {
                int row = bm + wm * 64 + mi * 16 + (lane >> 4) * 4 + r;
                int prow = row & (POSROWS - 1);
                out[(size_t)row * NN + col] =
                    acc[mi][ni][r] + bcol + pos[(size_t)prow * NN + col];
            }
        }
    }
}

// ---------------- fallback (ws too small): naive fp32 ----------------

__global__ void fb_kernel(const float* __restrict__ A, const float* __restrict__ W,
                          const float* __restrict__ bias, const float* __restrict__ pt,
                          float* __restrict__ out) {
    __shared__ float sA[16][17], sB[16][17];
    int ty = threadIdx.y, tx = threadIdx.x;
    int row = blockIdx.y * 16 + ty; // M
    int col = blockIdx.x * 16 + tx; // N
    float acc = 0.f;
    for (int k0 = 0; k0 < KK; k0 += 16) {
        int ka = k0 + tx;
        sA[ty][tx] = (ka < KK) ? A[(size_t)row * KK + ka] : 0.f;
        sB[ty][tx] = (ka < KK) ? W[(size_t)(blockIdx.x * 16 + ty) * KK + ka] : 0.f;
        __syncthreads();
        #pragma unroll
        for (int kk = 0; kk < 16; ++kk)
            acc += sA[ty][kk] * sB[tx][kk];
        __syncthreads();
    }
    int n = row & (POSROWS - 1);
    int h = ((n >> 7) << 1) | ((n >> 1) & 1);
    int w = (((n >> 2) & 31) << 1) | (n & 1);
    float wh[4], ww[4]; int ih[4], iw[4];
    cubic_taps(h, wh, ih);
    cubic_taps(w, ww, iw);
    float p = 0.f;
    #pragma unroll
    for (int a = 0; a < 4; ++a) {
        float rs = 0.f;
        #pragma unroll
        for (int b = 0; b < 4; ++b)
            rs += ww[b] * pt[(ih[a] * 16 + iw[b]) * NN + col];
        p += wh[a] * rs;
    }
    out[(size_t)row * NN + col] = acc + bias[col] + p;
}

// ---------------- launch ----------------

extern "C" void kernel_launch(void* const* d_in, const int* in_sizes, int n_in,
                              void* d_out, int out_size, void* d_ws, size_t ws_size,
                              hipStream_t stream) {
    const float* pv   = (const float*)d_in[0]; // (32768, 588)
    const float* wp   = (const float*)d_in[1]; // (1152, 588)
    const float* bias = (const float*)d_in[2]; // (1152,)
    const float* pt   = (const float*)d_in[3]; // (256, 1152)
    float* out = (float*)d_out;

    const size_t pos_bytes = (size_t)POSROWS * NN * 4;   // 18,874,368
    const size_t pvb_bytes = (size_t)MM * KP * 2;        // 39,845,888
    const size_t wb_bytes  = (size_t)NN * KP * 2;        //  1,400,832
    const size_t need = pos_bytes + pvb_bytes + wb_bytes;

    if (ws_size >= need) {
        float* pos = (float*)d_ws;
        ushort_t* pvb = (ushort_t*)((char*)d_ws + pos_bytes);
        ushort_t* wb  = (ushort_t*)((char*)d_ws + pos_bytes + pvb_bytes);

        pos_kernel<<<POSROWS, 320, 0, stream>>>(pt, pos);

        int ca = MM * CHUNKS_PER_ROW;
        cvt_pad_kernel<<<(ca + 255) / 256, 256, 0, stream>>>(pv, pvb, MM);
        int cb = NN * CHUNKS_PER_ROW;
        cvt_pad_kernel<<<(cb + 255) / 256, 256, 0, stream>>>(wp, wb, NN);

        gemm_kernel<<<GRID, 256, 0, stream>>>(pvb, wb, bias, pos, out);
    } else {
        fb_kernel<<<dim3(NN / 16, MM / 16), dim3(16, 16), 0, stream>>>(pv, wp, bias, pt, out);
    }
}